// Round 9
// baseline (505.787 us; speedup 1.0000x reference)
//
#include <hip/hip_runtime.h>
#include <hip/hip_fp8.h>
#include <math.h>

#define N_ROWS 8192
#define IN_F   512
#define RFF    2048
#define OUT_F  1000
#define OUT_PAD 1024
#define INV_RFF_SCALAR 0.03125f
#define MEAN_FIELD 25.0f
#define PHI_NT 24   /* K = 1536 (concat hh|hl|lh), BK = 64 */
#define PRED_NT 32  /* K = 2048, BK = 64 */

typedef __attribute__((ext_vector_type(8))) short short8;
typedef __attribute__((ext_vector_type(4))) float f32x4;
typedef __attribute__((ext_vector_type(2))) long long2v;

// ---------- bf16 helpers (RTN-even) ----------
__device__ __forceinline__ unsigned short f32_to_bf16(float f) {
    unsigned u = __float_as_uint(f);
    unsigned r = 0x7FFFu + ((u >> 16) & 1u);
    return (unsigned short)((u + r) >> 16);
}
__device__ __forceinline__ float bf16_to_f32(unsigned short h) {
    return __uint_as_float(((unsigned)h) << 16);
}
__device__ __forceinline__ unsigned char f32_to_fp8(float x) {
    __hip_fp8_e4m3 q(x);           // OCP e4m3fn, HW RNE convert
    return (unsigned char)q.__x;
}

// fp8 permuted packing within each 64-element k-block:
// pos(k) = (k & ~63) + quad*16 + s*8 + j   (quad=(k>>3)&3, s=(k>>5)&1, j=k&7)
__device__ __forceinline__ int perm64(int k) {
    return (k & ~63) | (((k >> 3) & 3) << 4) | (((k >> 5) & 1) << 3) | (k & 7);
}

// ---- fp8 staging, K=128-byte tile (diag): 4 loads/thread ----
__device__ __forceinline__ void stage_tile8(const unsigned char* __restrict__ X,
                                            int r0, int k0b, unsigned char* lds,
                                            int w, int lane) {
    #pragma unroll
    for (int h = 0; h < 4; ++h) {
        int qb = h * 256 + w * 64;
        int q = qb + lane;
        int rt = q >> 7, c = (q >> 4) & 7, r = q & 15;
        const void* g = X + (size_t)(r0 + rt * 16 + r) * RFF + k0b + c * 16;
        __builtin_amdgcn_global_load_lds(
            (const __attribute__((address_space(1))) void*)g,
            (__attribute__((address_space(3))) void*)(lds + qb * 16),
            16, 0, 0);
    }
}

// =====================================================================
// mega_conv: all independent input conversions + buffer zeroing in ONE
// launch (blockIdx-range dispatch) — replaces 4 kernels + hipMemset.
//   [0,4096)       conv_split : D -> Dh, Dl
//   [4096,4352)    conv_wt    : W -> Wth, Wtl (transposed hi/lo)
//   [4352,6400)    conv_lw    : Lw -> Lw16 (padded bf16)
//   [6400,10496)   conv_covu8 : cov -> CovU8 (fp8, perm64) + Cd
//   [10496,10504)  zero diag
//   [10504]        zero strip counters
// =====================================================================
__global__ __launch_bounds__(256) void mega_conv_kernel(
    const float* __restrict__ D, const float* __restrict__ W,
    const float* __restrict__ Lw, const float* __restrict__ cov,
    unsigned short* __restrict__ Dh, unsigned short* __restrict__ Dl,
    unsigned short* __restrict__ Wth, unsigned short* __restrict__ Wtl,
    unsigned short* __restrict__ Lw16, unsigned char* __restrict__ CovU8,
    float* __restrict__ Cd, float* __restrict__ diag, int* __restrict__ cnt)
{
    __shared__ float tile[64][65];
    const int bid = blockIdx.x;
    const int tid = threadIdx.x;

    if (bid < 4096) {
        // ---- conv_split ----
        int i = bid * 256 + tid;
        float4 v = ((const float4*)D)[i];
        ushort4 h, l;
        h.x = f32_to_bf16(v.x); l.x = f32_to_bf16(v.x - bf16_to_f32(h.x));
        h.y = f32_to_bf16(v.y); l.y = f32_to_bf16(v.y - bf16_to_f32(h.y));
        h.z = f32_to_bf16(v.z); l.z = f32_to_bf16(v.z - bf16_to_f32(h.z));
        h.w = f32_to_bf16(v.w); l.w = f32_to_bf16(v.w - bf16_to_f32(h.w));
        ((ushort4*)Dh)[i] = h;
        ((ushort4*)Dl)[i] = l;
    } else if (bid < 4352) {
        // ---- conv_wt (64x64 transpose tiles) ----
        int b = bid - 4096;
        const int n0 = (b & 31) * 64;
        const int k0 = (b >> 5) * 64;
        #pragma unroll
        for (int i = 0; i < 16; ++i) {
            int e = i * 256 + tid;
            int r = e >> 6, c = e & 63;
            tile[r][c] = W[(size_t)(k0 + r) * RFF + n0 + c];
        }
        __syncthreads();
        #pragma unroll
        for (int i = 0; i < 16; ++i) {
            int e = i * 256 + tid;
            int r = e >> 6, c = e & 63;
            float v = tile[c][r];
            unsigned short h = f32_to_bf16(v);
            unsigned short l = f32_to_bf16(v - bf16_to_f32(h));
            Wth[(size_t)(n0 + r) * IN_F + k0 + c] = h;
            Wtl[(size_t)(n0 + r) * IN_F + k0 + c] = l;
        }
    } else if (bid < 6400) {
        // ---- conv_lw ----
        int i = (bid - 4352) * 256 + tid;
        int base = i * 4;
        int row = base >> 11;
        ushort4 o;
        if (row < OUT_F) {
            float4 v = ((const float4*)Lw)[i];
            o.x = f32_to_bf16(v.x); o.y = f32_to_bf16(v.y);
            o.z = f32_to_bf16(v.z); o.w = f32_to_bf16(v.w);
        } else {
            o.x = o.y = o.z = o.w = 0;
        }
        ((ushort4*)Lw16)[i] = o;
    } else if (bid < 10496) {
        // ---- conv_covu8 (+ diagonal extract) ----
        int i = (bid - 6400) * 256 + tid;
        int base = i * 4;
        int row = base >> 11;
        int col = base & 2047;
        int bn = row >> 7, bk = col >> 7;
        float w = (bk < bn) ? 16.0f : (bk == bn ? 8.0f : 0.0f);
        float4 v = ((const float4*)cov)[i];
        float vv[4] = {v.x, v.y, v.z, v.w};
        float wj[4];
        #pragma unroll
        for (int j = 0; j < 4; ++j) {
            if (col + j == row) { wj[j] = 0.0f; Cd[row] = vv[j]; }
            else wj[j] = w;
        }
        uchar4 o;
        o.x = f32_to_fp8(vv[0] * wj[0]); o.y = f32_to_fp8(vv[1] * wj[1]);
        o.z = f32_to_fp8(vv[2] * wj[2]); o.w = f32_to_fp8(vv[3] * wj[3]);
        *(uchar4*)(CovU8 + (size_t)row * RFF + perm64(col)) = o;
    } else if (bid < 10504) {
        // ---- zero diag ----
        int idx = (bid - 10496) * 256 + tid;
        ((float4*)diag)[idx] = (float4){0.f, 0.f, 0.f, 0.f};
    } else {
        // ---- zero strip counters ----
        if (tid < 64) cnt[tid] = 0;
    }
}

// ===================== phi staging machinery (unchanged) =====================

__device__ __forceinline__ void gload16u(const void* g, unsigned short* lds) {
    __builtin_amdgcn_global_load_lds(
        (const __attribute__((address_space(1))) void*)g,
        (__attribute__((address_space(3))) void*)lds, 16, 0, 0);
}

__device__ __forceinline__ void stage_ab(const unsigned short* __restrict__ src,
                                         int stride, int r0v, int kk,
                                         unsigned short* ldsbuf,
                                         int Qa, int h, int w, int lane) {
    int q   = w * 64 + lane;
    int RT  = h * 8 + Qa * 4 + (q >> 7);
    int c   = (q >> 4) & 7, r = q & 15;
    const void* g = src + (size_t)(r0v + RT * 16 + r) * stride + kk + c * 8;
    int RTu = h * 8 + Qa * 4 + (w >> 1);
    int cu  = (w & 1) * 4;
    gload16u(g, ldsbuf + RTu * 1024 + cu * 128);
}

__device__ __forceinline__ void stageB_g(const unsigned short* __restrict__ src,
                                         int cc0, int kk, unsigned short* ldsbuf,
                                         int nh, int h, int w, int lane) {
    int q    = w * 64 + lane;
    int i    = q >> 7;
    int RTp  = (i >> 1) * 4 + nh * 2 + (i & 1);
    int c    = (q >> 4) & 7, r = q & 15;
    const void* g = src + (size_t)(cc0 + h * 128 + RTp * 16 + r) * IN_F + kk + c * 8;
    int iu   = w >> 1;
    int RTpu = (iu >> 1) * 4 + nh * 2 + (iu & 1);
    int RTu  = h * 8 + RTpu;
    int cu   = (w & 1) * 4;
    gload16u(g, ldsbuf + RTu * 1024 + cu * 128);
}

#define SB0() __builtin_amdgcn_sched_barrier(0)
#define BARRIER() do { SB0(); __builtin_amdgcn_s_barrier(); SB0(); } while (0)
#define WAITVM(N) do { asm volatile("s_waitcnt vmcnt(" #N ")"); SB0(); } while (0)

// =====================================================================
// Kernel 1: Phi = cos(D@W + b)/32 — K-concat 1536, 256x256 tile,
// 4-phase counted-vmcnt pipeline (validated r2-r7 — UNCHANGED).
// =====================================================================

#define READ_FA(FA, mh) do {                                                  \
    _Pragma("unroll")                                                         \
    for (int i_ = 0; i_ < 4; ++i_) {                                          \
        FA[i_][0] = *(const short8*)(A + (wm * 8 + (mh) * 4 + i_) * 1024      \
                                       + quad * 128 + ln * 8);                \
        FA[i_][1] = *(const short8*)(A + (wm * 8 + (mh) * 4 + i_) * 1024      \
                                       + 512 + quad * 128 + ln * 8);          \
    } } while (0)

#define READ_FB(FB, nh) do {                                                  \
    _Pragma("unroll")                                                         \
    for (int j_ = 0; j_ < 2; ++j_) {                                          \
        FB[j_][0] = *(const short8*)(B + (wn * 4 + (nh) * 2 + j_) * 1024      \
                                       + quad * 128 + ln * 8);                \
        FB[j_][1] = *(const short8*)(B + (wn * 4 + (nh) * 2 + j_) * 1024      \
                                       + 512 + quad * 128 + ln * 8);          \
    } } while (0)

#define MFMA16(MH, NH, FA, FB) do {                                           \
    __builtin_amdgcn_s_setprio(1);                                            \
    _Pragma("unroll")                                                         \
    for (int s_ = 0; s_ < 2; ++s_)                                            \
        _Pragma("unroll")                                                     \
        for (int i_ = 0; i_ < 4; ++i_)                                        \
            _Pragma("unroll")                                                 \
            for (int j_ = 0; j_ < 2; ++j_)                                    \
                acc[(MH) * 4 + i_][(NH) * 2 + j_] =                           \
                    __builtin_amdgcn_mfma_f32_16x16x32_bf16(                  \
                        FA[i_][s_], FB[j_][s_],                               \
                        acc[(MH) * 4 + i_][(NH) * 2 + j_], 0, 0, 0);          \
    __builtin_amdgcn_s_setprio(0);                                            \
} while (0)

__global__ __launch_bounds__(512, 2) void phi_mfma8p_kernel(
    const unsigned short* __restrict__ Dh, const unsigned short* __restrict__ Dl,
    const unsigned short* __restrict__ Wth, const unsigned short* __restrict__ Wtl,
    const float* __restrict__ bias, unsigned short* __restrict__ Phi)
{
    __shared__ unsigned short ldsA[2 * 16384];
    __shared__ unsigned short ldsB[2 * 16384];
    const int tid = threadIdx.x;
    const int w = tid >> 6, lane = tid & 63;
    const int wm = w >> 2, wn = w & 3;
    const int quad = lane >> 4, ln = lane & 15;

    const int bid = blockIdx.x;
    const int xcd = bid & 7, idx = bid >> 3;
    const int rb = (xcd >> 1) * 8 + (idx & 7);
    const int cb = (xcd & 1) * 4 + (idx >> 3);
    const int r0 = rb * 256;
    const int c0 = cb * 256;

    f32x4 acc[8][4];
    #pragma unroll
    for (int i = 0; i < 8; ++i)
        #pragma unroll
        for (int j = 0; j < 4; ++j)
            acc[i][j] = (f32x4)(0.0f);

    stage_ab(Dh, IN_F, r0, 0, ldsA, 0, 0, w, lane);
    stage_ab(Dh, IN_F, r0, 0, ldsA, 0, 1, w, lane);
    stage_ab(Dh, IN_F, r0, 0, ldsA, 1, 0, w, lane);
    stage_ab(Dh, IN_F, r0, 0, ldsA, 1, 1, w, lane);
    stageB_g(Wth, c0, 0, ldsB, 0, 0, w, lane);
    stageB_g(Wth, c0, 0, ldsB, 0, 1, w, lane);
    stageB_g(Wth, c0, 0, ldsB, 1, 0, w, lane);
    stageB_g(Wth, c0, 0, ldsB, 1, 1, w, lane);
    stage_ab(Dh, IN_F, r0, 64, ldsA + 16384, 0, 0, w, lane);
    stage_ab(Dh, IN_F, r0, 64, ldsA + 16384, 0, 1, w, lane);
    stageB_g(Wth, c0, 64, ldsB + 16384, 0, 0, w, lane);
    stageB_g(Wth, c0, 64, ldsB + 16384, 0, 1, w, lane);
    WAITVM(4);
    BARRIER();

    for (int t = 0; t < PHI_NT - 1; ++t) {
        const int buf = t & 1;
        const unsigned short* A = ldsA + buf * 16384;
        const unsigned short* B = ldsB + buf * 16384;
        unsigned short* curA = ldsA + buf * 16384;
        unsigned short* curB = ldsB + buf * 16384;
        unsigned short* othA = ldsA + (buf ^ 1) * 16384;
        unsigned short* othB = ldsB + (buf ^ 1) * 16384;
        const bool has2 = (t + 2) < PHI_NT;
        const int k1 = (t + 1) * 64, k2 = (t + 2) * 64;
        const int kk1 = k1 & 511, kk2 = k2 & 511;
        const unsigned short* A1 = (k1 >= 1024) ? Dl : Dh;
        const unsigned short* B1 = (k1 >= 1024) ? Wth : (k1 >= 512 ? Wtl : Wth);
        const unsigned short* A2 = (k2 >= 1024) ? Dl : Dh;
        const unsigned short* B2 = (k2 >= 1024) ? Wth : (k2 >= 512 ? Wtl : Wth);

        short8 fa[4][2], fb0[2][2], fb1[2][2];

        READ_FA(fa, 0);
        READ_FB(fb0, 0);
        stage_ab(A1, IN_F, r0, kk1, othA, 1, 0, w, lane);
        stage_ab(A1, IN_F, r0, kk1, othA, 1, 1, w, lane);
        BARRIER();
        MFMA16(0, 0, fa, fb0);
        BARRIER();

        READ_FB(fb1, 1);
        stageB_g(B1, c0, kk1, othB, 1, 0, w, lane);
        stageB_g(B1, c0, kk1, othB, 1, 1, w, lane);
        BARRIER();
        MFMA16(0, 1, fa, fb1);
        BARRIER();

        READ_FA(fa, 1);
        if (has2) { stage_ab(A2, IN_F, r0, kk2, curA, 0, 0, w, lane);
                    stage_ab(A2, IN_F, r0, kk2, curA, 0, 1, w, lane); }
        BARRIER();
        MFMA16(1, 0, fa, fb0);
        BARRIER();

        if (has2) { stageB_g(B2, c0, kk2, curB, 0, 0, w, lane);
                    stageB_g(B2, c0, kk2, curB, 0, 1, w, lane);
                    WAITVM(4); }
        else      { WAITVM(0); }
        BARRIER();
        MFMA16(1, 1, fa, fb1);
        BARRIER();
    }

    {
        asm volatile("" ::: "memory");
        const unsigned short* A = ldsA + ((PHI_NT - 1) & 1) * 16384;
        const unsigned short* B = ldsB + ((PHI_NT - 1) & 1) * 16384;
        short8 fa[4][2], fb0[2][2], fb1[2][2];
        READ_FA(fa, 0);
        READ_FB(fb0, 0);
        READ_FB(fb1, 1);
        MFMA16(0, 0, fa, fb0);
        MFMA16(0, 1, fa, fb1);
        READ_FA(fa, 1);
        MFMA16(1, 0, fa, fb0);
        MFMA16(1, 1, fa, fb1);
    }

    float bv[4];
    #pragma unroll
    for (int nt = 0; nt < 4; ++nt)
        bv[nt] = bias[c0 + wn * 64 + nt * 16 + ln];
    #pragma unroll
    for (int mt = 0; mt < 8; ++mt)
        #pragma unroll
        for (int nt = 0; nt < 4; ++nt) {
            int col = c0 + wn * 64 + nt * 16 + ln;
            #pragma unroll
            for (int reg = 0; reg < 4; ++reg) {
                int row = r0 + wm * 128 + mt * 16 + quad * 4 + reg;
                float z = acc[mt][nt][reg] + bv[nt];
                float p = __cosf(z) * INV_RFF_SCALAR;
                Phi[(size_t)row * RFF + col] = f32_to_bf16(p);
            }
        }
}

// =====================================================================
// Kernel 2: pred_conv8 — r4's best pred (min-2-phase counted, 77 µs)
// + conv_phi8 as 128 role-blocks in the same launch.
//   bid [0,128)   : conv_phi8 role, rows [bid*64, bid*64+64)
//   bid [128,384) : pred role (pb = bid-128, EXACTLY 256 blocks —
//                   r8's 512 was the OOB crash), raw-acc store to out
// =====================================================================
__global__ __launch_bounds__(512, 2) void pred_conv8_kernel(
    const unsigned short* __restrict__ Phi, const unsigned short* __restrict__ Lw,
    unsigned char* __restrict__ Phi8, float* __restrict__ out)
{
    __shared__ unsigned short ldsA[2 * 16384];   // 64 KiB
    __shared__ unsigned short ldsB[2 * 8192];    // 32 KiB
    const int tid = threadIdx.x;

    if (blockIdx.x < 128) {
        // ---- conv_phi8 role: 64 rows/block, 512 threads ----
        const int row0 = blockIdx.x * 64;
        #pragma unroll 4
        for (int e = tid; e < 64 * (RFF / 4); e += 512) {
            int r = e >> 9;            // RFF/4 = 512 groups per row
            int g = e & 511;
            int row = row0 + r;
            int col = g * 4;
            ushort4 v = *(const ushort4*)(Phi + (size_t)row * RFF + col);
            uchar4 o;
            o.x = f32_to_fp8(bf16_to_f32(v.x) * 32.0f);
            o.y = f32_to_fp8(bf16_to_f32(v.y) * 32.0f);
            o.z = f32_to_fp8(bf16_to_f32(v.z) * 32.0f);
            o.w = f32_to_fp8(bf16_to_f32(v.w) * 32.0f);
            *(uchar4*)(Phi8 + (size_t)row * RFF + perm64(col)) = o;
        }
        return;
    }

    const int w = tid >> 6, lane = tid & 63;
    const int wm = w >> 1, wn = w & 1;           // 4M x 2N wave grid, 64x64/wave
    const int quad = lane >> 4, ln = lane & 15;

    // XCD-aware: each XCD owns 4 contiguous row-strips x all 8 col-blocks
    // pb in [0,256): xcd = pb&7, idx = pb>>3 in [0,32) -> rb in [0,32), cb in [0,8)
    const int pb = blockIdx.x - 128;
    const int xcd = pb & 7, idx = pb >> 3;
    const int rb = xcd * 4 + (idx >> 3);
    const int cb = idx & 7;
    const int r0 = rb * 256;
    const int c0 = cb * 128;

    f32x4 acc[4][4];
    #pragma unroll
    for (int i = 0; i < 4; ++i)
        #pragma unroll
        for (int j = 0; j < 4; ++j)
            acc[i][j] = (f32x4)(0.0f);

    // prologue: tile 0 -> buf0 (6 calls)
    stage_ab(Phi, RFF, r0, 0, ldsA, 0, 0, w, lane);
    stage_ab(Phi, RFF, r0, 0, ldsA, 1, 0, w, lane);
    stage_ab(Phi, RFF, r0, 0, ldsA, 0, 1, w, lane);
    stage_ab(Phi, RFF, r0, 0, ldsA, 1, 1, w, lane);
    stage_ab(Lw,  RFF, c0, 0, ldsB, 0, 0, w, lane);
    stage_ab(Lw,  RFF, c0, 0, ldsB, 1, 0, w, lane);
    WAITVM(0);
    BARRIER();

    for (int t = 0; t < PRED_NT; ++t) {
        const int buf = t & 1;
        const unsigned short* A = ldsA + buf * 16384;
        const unsigned short* B = ldsB + buf * 8192;

        // issue-early: stage tile t+1 into the other buffer
        if (t + 1 < PRED_NT) {
            const int kk = (t + 1) * 64;
            unsigned short* nA = ldsA + (buf ^ 1) * 16384;
            unsigned short* nB = ldsB + (buf ^ 1) * 8192;
            stage_ab(Phi, RFF, r0, kk, nA, 0, 0, w, lane);
            stage_ab(Phi, RFF, r0, kk, nA, 1, 0, w, lane);
            stage_ab(Phi, RFF, r0, kk, nA, 0, 1, w, lane);
            stage_ab(Phi, RFF, r0, kk, nA, 1, 1, w, lane);
            stage_ab(Lw,  RFF, c0, kk, nB, 0, 0, w, lane);
            stage_ab(Lw,  RFF, c0, kk, nB, 1, 0, w, lane);
        }

        // fat compute phase: 16 ds_read_b128 + 32 MFMA
        short8 fa[4][2], fb[4][2];
        #pragma unroll
        for (int i_ = 0; i_ < 4; ++i_) {
            fa[i_][0] = *(const short8*)(A + (wm * 4 + i_) * 1024 + quad * 128 + ln * 8);
            fa[i_][1] = *(const short8*)(A + (wm * 4 + i_) * 1024 + 512 + quad * 128 + ln * 8);
        }
        #pragma unroll
        for (int j_ = 0; j_ < 4; ++j_) {
            fb[j_][0] = *(const short8*)(B + (wn * 4 + j_) * 1024 + quad * 128 + ln * 8);
            fb[j_][1] = *(const short8*)(B + (wn * 4 + j_) * 1024 + 512 + quad * 128 + ln * 8);
        }
        __builtin_amdgcn_s_setprio(1);
        #pragma unroll
        for (int s_ = 0; s_ < 2; ++s_)
            #pragma unroll
            for (int i_ = 0; i_ < 4; ++i_)
                #pragma unroll
                for (int j_ = 0; j_ < 4; ++j_)
                    acc[i_][j_] = __builtin_amdgcn_mfma_f32_16x16x32_bf16(
                        fa[i_][s_], fb[j_][s_], acc[i_][j_], 0, 0, 0);
        __builtin_amdgcn_s_setprio(0);

        WAITVM(0);
        BARRIER();
    }

    // raw store (bias + scale applied by diag kernel's last-finisher)
    #pragma unroll
    for (int mt = 0; mt < 4; ++mt)
        #pragma unroll
        for (int nt = 0; nt < 4; ++nt) {
            int col = c0 + wn * 64 + nt * 16 + ln;
            if (col < OUT_F) {
                #pragma unroll
                for (int reg = 0; reg < 4; ++reg) {
                    int row = r0 + wm * 64 + mt * 16 + quad * 4 + reg;
                    out[(size_t)row * OUT_F + col] = acc[mt][nt][reg];
                }
            }
        }
}

// =====================================================================
// Kernel 3: diag (r0-validated body) + fused pred-epilogue via per-strip
// last-finisher: each 128-row strip has 16 J-blocks; the block that
// completes the strip (device-scope counter) applies
// out = (raw + Lb) / sqrt(1 + 25*diag) for the strip. diag values read
// back via atomic-RMW (device-coherent across XCDs). Deadlock-free
// (non-blocking, no co-residency assumption).
// =====================================================================
__global__ __launch_bounds__(256) void diag8_epi_kernel(
    const unsigned char* __restrict__ Phi8, const unsigned char* __restrict__ CovU8,
    const unsigned short* __restrict__ Phi16, const float* __restrict__ Cd,
    float* __restrict__ diag, int* __restrict__ cnt,
    float* __restrict__ out, const float* __restrict__ Lb)
{
    __shared__ __align__(16) unsigned char ldsA[16384];
    __shared__ __align__(16) unsigned char ldsB[16384];
    __shared__ float sS[128];
    __shared__ int lastFlag;
    const int tid = threadIdx.x;
    const int w = tid >> 6, lane = tid & 63;
    const int wm = w >> 1, wn = w & 1;
    const int quad = lane >> 4, ln = lane & 15;
    const int J = 15 - blockIdx.x;
    const int r0 = blockIdx.y * 128;
    const int c0 = J * 128;
    const int kmax = (J + 1) * 128;

    f32x4 acc[4][4];
    #pragma unroll
    for (int i = 0; i < 4; ++i)
        #pragma unroll
        for (int j = 0; j < 4; ++j)
            acc[i][j] = (f32x4)(0.0f);

    for (int k0 = 0; k0 < kmax; k0 += 128) {
        __syncthreads();
        stage_tile8(Phi8,  r0, k0, ldsA, w, lane);
        stage_tile8(CovU8, c0, k0, ldsB, w, lane);
        __syncthreads();

        #pragma unroll
        for (int kb = 0; kb < 2; ++kb) {
            long2v fa[4], fb[4];
            #pragma unroll
            for (int t = 0; t < 4; ++t) {
                fa[t] = *(const long2v*)(ldsA + (((wm * 4 + t) * 128 + (kb * 4 + quad) * 16 + ln) << 4));
                fb[t] = *(const long2v*)(ldsB + (((wn * 4 + t) * 128 + (kb * 4 + quad) * 16 + ln) << 4));
            }
            #pragma unroll
            for (int mt = 0; mt < 4; ++mt)
                #pragma unroll
                for (int nt = 0; nt < 4; ++nt)
                    acc[mt][nt] = __builtin_amdgcn_mfma_f32_16x16x32_fp8_fp8(
                        fa[mt].x, fb[nt].x, acc[mt][nt], 0, 0, 0);
            #pragma unroll
            for (int mt = 0; mt < 4; ++mt)
                #pragma unroll
                for (int nt = 0; nt < 4; ++nt)
                    acc[mt][nt] = __builtin_amdgcn_mfma_f32_16x16x32_fp8_fp8(
                        fa[mt].y, fb[nt].y, acc[mt][nt], 0, 0, 0);
        }
    }

    float cd[4];
    #pragma unroll
    for (int nt = 0; nt < 4; ++nt)
        cd[nt] = 256.0f * Cd[c0 + wn * 64 + nt * 16 + ln];
    #pragma unroll
    for (int mt = 0; mt < 4; ++mt) {
        float psum[4] = {0.f, 0.f, 0.f, 0.f};
        #pragma unroll
        for (int nt = 0; nt < 4; ++nt) {
            int col = c0 + wn * 64 + nt * 16 + ln;
            #pragma unroll
            for (int reg = 0; reg < 4; ++reg) {
                int row = r0 + wm * 64 + mt * 16 + quad * 4 + reg;
                float pv = bf16_to_f32(Phi16[(size_t)row * RFF + col]);
                psum[reg] = fmaf(fmaf(cd[nt], pv, acc[mt][nt][reg]), pv, psum[reg]);
            }
        }
        #pragma unroll
        for (int off = 1; off < 16; off <<= 1)
            #pragma unroll
            for (int reg = 0; reg < 4; ++reg)
                psum[reg] += __shfl_xor(psum[reg], off, 16);
        if (ln == 0) {
            #pragma unroll
            for (int reg = 0; reg < 4; ++reg) {
                int row = r0 + wm * 64 + mt * 16 + quad * 4 + reg;
                atomicAdd(&diag[row], psum[reg] * (1.0f / 256.0f));
            }
        }
    }

    // ---- per-strip last-finisher epilogue ----
    __syncthreads();          // all waves' diag atomics issued
    __threadfence();          // release: make them device-visible
    if (tid == 0)
        lastFlag = (atomicAdd(&cnt[blockIdx.y], 1) == 15) ? 1 : 0;
    __syncthreads();
    if (lastFlag) {
        if (tid < 128) {
            float dv = atomicAdd(&diag[r0 + tid], 0.0f);   // coherent read
            sS[tid] = 1.0f / sqrtf(1.0f + MEAN_FIELD * dv);
        }
        __syncthreads();
        for (int e = tid; e < 128 * 250; e += 256) {
            int rr = e / 250;
            int ccg = e - rr * 250;
            int cc = ccg * 4;
            int row = r0 + rr;
            float s = sS[rr];
            float4 v = *(float4*)(out + (size_t)row * OUT_F + cc);
            float4 b = *(const float4*)(Lb + cc);
            v.x = (v.x + b.x) * s;
            v.y = (v.y + b.y) * s;
            v.z = (v.z + b.z) * s;
            v.w = (v.w + b.w) * s;
            *(float4*)(out + (size_t)row * OUT_F + cc) = v;
        }
    }
}

extern "C" void kernel_launch(void* const* d_in, const int* in_sizes, int n_in,
                              void* d_out, int out_size, void* d_ws, size_t ws_size,
                              hipStream_t stream) {
    const float* D    = (const float*)d_in[0];
    const float* W    = (const float*)d_in[1];
    const float* bias = (const float*)d_in[2];
    const float* Lw   = (const float*)d_in[3];
    const float* Lb   = (const float*)d_in[4];
    const float* cov  = (const float*)d_in[5];
    float* out = (float*)d_out;

    char* p = (char*)d_ws;
    unsigned short* Phi16 = (unsigned short*)p;  p += (size_t)N_ROWS * RFF * 2;   // 32 MiB
    unsigned char*  Phi8  = (unsigned char*)p;   // alias of Dh+Dl region (16 MiB)
    unsigned short* Dh    = (unsigned short*)p;  p += (size_t)N_ROWS * IN_F * 2;  // 8 MiB
    unsigned short* Dl    = (unsigned short*)p;  p += (size_t)N_ROWS * IN_F * 2;  // 8 MiB
    unsigned short* Wth   = (unsigned short*)p;  p += (size_t)RFF * IN_F * 2;     // 2 MiB
    unsigned short* Wtl   = (unsigned short*)p;  p += (size_t)RFF * IN_F * 2;     // 2 MiB
    unsigned short* Lw16  = (unsigned short*)p;  p += (size_t)OUT_PAD * RFF * 2;  // 4 MiB
    unsigned char*  CovU8 = (unsigned char*)p;                                    // 4 MiB used
    float*          Cd    = (float*)(p + (size_t)RFF * RFF);                      // 8 KiB (in pad)
    int*            cnt   = (int*)(p + (size_t)RFF * RFF + 8192);                 // 256 B (in pad)
    p += (size_t)RFF * RFF * 2;                                                   // 8 MiB region
    float* diag           = (float*)p;                                            // 32 KiB

    mega_conv_kernel<<<dim3(10505), dim3(256), 0, stream>>>(
        D, W, Lw, cov, Dh, Dl, Wth, Wtl, Lw16, CovU8, Cd, diag, cnt);

    phi_mfma8p_kernel<<<dim3(256), dim3(512), 0, stream>>>(Dh, Dl, Wth, Wtl, bias, Phi16);

    pred_conv8_kernel<<<dim3(384), dim3(512), 0, stream>>>(Phi16, Lw16, Phi8, out);

    diag8_epi_kernel<<<dim3(16, 64), dim3(256), 0, stream>>>(
        Phi8, CovU8, Phi16, Cd, diag, cnt, out, Lb);
}

// Round 10
// 308.317 us; speedup vs baseline: 1.6405x; 1.6405x over previous
//
#include <hip/hip_runtime.h>
#include <hip/hip_fp8.h>
#include <math.h>

#define N_ROWS 8192
#define IN_F   512
#define RFF    2048
#define OUT_F  1000
#define OUT_PAD 1024
#define INV_RFF_SCALAR 0.03125f
#define MEAN_FIELD 25.0f
#define PHI_NT 24   /* K = 1536 (concat hh|hl|lh), BK = 64 */
#define PRED_NT 32  /* K = 2048, BK = 64 */

typedef __attribute__((ext_vector_type(8))) short short8;
typedef __attribute__((ext_vector_type(4))) float f32x4;
typedef __attribute__((ext_vector_type(2))) long long2v;

// ---------- bf16 helpers (RTN-even) ----------
__device__ __forceinline__ unsigned short f32_to_bf16(float f) {
    unsigned u = __float_as_uint(f);
    unsigned r = 0x7FFFu + ((u >> 16) & 1u);
    return (unsigned short)((u + r) >> 16);
}
__device__ __forceinline__ float bf16_to_f32(unsigned short h) {
    return __uint_as_float(((unsigned)h) << 16);
}
__device__ __forceinline__ unsigned char f32_to_fp8(float x) {
    __hip_fp8_e4m3 q(x);           // OCP e4m3fn, HW RNE convert
    return (unsigned char)q.__x;
}

// fp8 permuted packing within each 64-element k-block:
// pos(k) = (k & ~63) + quad*16 + s*8 + j   (quad=(k>>3)&3, s=(k>>5)&1, j=k&7)
__device__ __forceinline__ int perm64(int k) {
    return (k & ~63) | (((k >> 3) & 3) << 4) | (((k >> 5) & 1) << 3) | (k & 7);
}

// ---- fp8 staging, K=128-byte tile (diag): 4 loads/thread ----
__device__ __forceinline__ void stage_tile8(const unsigned char* __restrict__ X,
                                            int r0, int k0b, unsigned char* lds,
                                            int w, int lane) {
    #pragma unroll
    for (int h = 0; h < 4; ++h) {
        int qb = h * 256 + w * 64;
        int q = qb + lane;
        int rt = q >> 7, c = (q >> 4) & 7, r = q & 15;
        const void* g = X + (size_t)(r0 + rt * 16 + r) * RFF + k0b + c * 16;
        __builtin_amdgcn_global_load_lds(
            (const __attribute__((address_space(1))) void*)g,
            (__attribute__((address_space(3))) void*)(lds + qb * 16),
            16, 0, 0);
    }
}

// =====================================================================
// mega_conv: all independent input conversions + diag zeroing in ONE
// launch (blockIdx-range dispatch).
//   [0,4096)       conv_split : D -> Dh, Dl
//   [4096,4352)    conv_wt    : W -> Wth, Wtl (transposed hi/lo)
//   [4352,6400)    conv_lw    : Lw -> Lw16 (padded bf16)
//   [6400,10496)   conv_covu8 : cov -> CovU8 (fp8, perm64) + Cd
//   [10496,10504)  zero diag
// =====================================================================
__global__ __launch_bounds__(256) void mega_conv_kernel(
    const float* __restrict__ D, const float* __restrict__ W,
    const float* __restrict__ Lw, const float* __restrict__ cov,
    unsigned short* __restrict__ Dh, unsigned short* __restrict__ Dl,
    unsigned short* __restrict__ Wth, unsigned short* __restrict__ Wtl,
    unsigned short* __restrict__ Lw16, unsigned char* __restrict__ CovU8,
    float* __restrict__ Cd, float* __restrict__ diag)
{
    __shared__ float tile[64][65];
    const int bid = blockIdx.x;
    const int tid = threadIdx.x;

    if (bid < 4096) {
        // ---- conv_split ----
        int i = bid * 256 + tid;
        float4 v = ((const float4*)D)[i];
        ushort4 h, l;
        h.x = f32_to_bf16(v.x); l.x = f32_to_bf16(v.x - bf16_to_f32(h.x));
        h.y = f32_to_bf16(v.y); l.y = f32_to_bf16(v.y - bf16_to_f32(h.y));
        h.z = f32_to_bf16(v.z); l.z = f32_to_bf16(v.z - bf16_to_f32(h.z));
        h.w = f32_to_bf16(v.w); l.w = f32_to_bf16(v.w - bf16_to_f32(h.w));
        ((ushort4*)Dh)[i] = h;
        ((ushort4*)Dl)[i] = l;
    } else if (bid < 4352) {
        // ---- conv_wt (64x64 transpose tiles) ----
        int b = bid - 4096;
        const int n0 = (b & 31) * 64;
        const int k0 = (b >> 5) * 64;
        #pragma unroll
        for (int i = 0; i < 16; ++i) {
            int e = i * 256 + tid;
            int r = e >> 6, c = e & 63;
            tile[r][c] = W[(size_t)(k0 + r) * RFF + n0 + c];
        }
        __syncthreads();
        #pragma unroll
        for (int i = 0; i < 16; ++i) {
            int e = i * 256 + tid;
            int r = e >> 6, c = e & 63;
            float v = tile[c][r];
            unsigned short h = f32_to_bf16(v);
            unsigned short l = f32_to_bf16(v - bf16_to_f32(h));
            Wth[(size_t)(n0 + r) * IN_F + k0 + c] = h;
            Wtl[(size_t)(n0 + r) * IN_F + k0 + c] = l;
        }
    } else if (bid < 6400) {
        // ---- conv_lw ----
        int i = (bid - 4352) * 256 + tid;
        int base = i * 4;
        int row = base >> 11;
        ushort4 o;
        if (row < OUT_F) {
            float4 v = ((const float4*)Lw)[i];
            o.x = f32_to_bf16(v.x); o.y = f32_to_bf16(v.y);
            o.z = f32_to_bf16(v.z); o.w = f32_to_bf16(v.w);
        } else {
            o.x = o.y = o.z = o.w = 0;
        }
        ((ushort4*)Lw16)[i] = o;
    } else if (bid < 10496) {
        // ---- conv_covu8 (+ diagonal extract) ----
        int i = (bid - 6400) * 256 + tid;
        int base = i * 4;
        int row = base >> 11;
        int col = base & 2047;
        int bn = row >> 7, bk = col >> 7;
        float w = (bk < bn) ? 16.0f : (bk == bn ? 8.0f : 0.0f);
        float4 v = ((const float4*)cov)[i];
        float vv[4] = {v.x, v.y, v.z, v.w};
        float wj[4];
        #pragma unroll
        for (int j = 0; j < 4; ++j) {
            if (col + j == row) { wj[j] = 0.0f; Cd[row] = vv[j]; }
            else wj[j] = w;
        }
        uchar4 o;
        o.x = f32_to_fp8(vv[0] * wj[0]); o.y = f32_to_fp8(vv[1] * wj[1]);
        o.z = f32_to_fp8(vv[2] * wj[2]); o.w = f32_to_fp8(vv[3] * wj[3]);
        *(uchar4*)(CovU8 + (size_t)row * RFF + perm64(col)) = o;
    } else {
        // ---- zero diag ----
        int idx = (bid - 10496) * 256 + tid;
        ((float4*)diag)[idx] = (float4){0.f, 0.f, 0.f, 0.f};
    }
}

// Phi16 -> Phi8 (fp8 e4m3, perm64 packing); standalone (fusing into phi
// or diag launches would be a same-launch producer/consumer race).
__global__ __launch_bounds__(256) void conv_phi8_kernel(
    const unsigned short* __restrict__ Phi16, unsigned char* __restrict__ Phi8)
{
    int i = blockIdx.x * 256 + threadIdx.x;
    int base = i * 4;
    int row = base >> 11;
    int col = base & 2047;
    ushort4 v = ((const ushort4*)Phi16)[i];
    uchar4 o;
    o.x = f32_to_fp8(bf16_to_f32(v.x) * 32.0f);
    o.y = f32_to_fp8(bf16_to_f32(v.y) * 32.0f);
    o.z = f32_to_fp8(bf16_to_f32(v.z) * 32.0f);
    o.w = f32_to_fp8(bf16_to_f32(v.w) * 32.0f);
    *(uchar4*)(Phi8 + (size_t)row * RFF + perm64(col)) = o;
}

// ===================== shared GEMM machinery =====================

__device__ __forceinline__ void gload16u(const void* g, unsigned short* lds) {
    __builtin_amdgcn_global_load_lds(
        (const __attribute__((address_space(1))) void*)g,
        (__attribute__((address_space(3))) void*)lds, 16, 0, 0);
}

__device__ __forceinline__ void stage_ab(const unsigned short* __restrict__ src,
                                         int stride, int r0v, int kk,
                                         unsigned short* ldsbuf,
                                         int Qa, int h, int w, int lane) {
    int q   = w * 64 + lane;
    int RT  = h * 8 + Qa * 4 + (q >> 7);
    int c   = (q >> 4) & 7, r = q & 15;
    const void* g = src + (size_t)(r0v + RT * 16 + r) * stride + kk + c * 8;
    int RTu = h * 8 + Qa * 4 + (w >> 1);
    int cu  = (w & 1) * 4;
    gload16u(g, ldsbuf + RTu * 1024 + cu * 128);
}

__device__ __forceinline__ void stageB_g(const unsigned short* __restrict__ src,
                                         int cc0, int kk, unsigned short* ldsbuf,
                                         int nh, int h, int w, int lane) {
    int q    = w * 64 + lane;
    int i    = q >> 7;
    int RTp  = (i >> 1) * 4 + nh * 2 + (i & 1);
    int c    = (q >> 4) & 7, r = q & 15;
    const void* g = src + (size_t)(cc0 + h * 128 + RTp * 16 + r) * IN_F + kk + c * 8;
    int iu   = w >> 1;
    int RTpu = (iu >> 1) * 4 + nh * 2 + (iu & 1);
    int RTu  = h * 8 + RTpu;
    int cu   = (w & 1) * 4;
    gload16u(g, ldsbuf + RTu * 1024 + cu * 128);
}

#define SB0() __builtin_amdgcn_sched_barrier(0)
#define BARRIER() do { SB0(); __builtin_amdgcn_s_barrier(); SB0(); } while (0)
#define WAITVM(N) do { asm volatile("s_waitcnt vmcnt(" #N ")"); SB0(); } while (0)

// =====================================================================
// Kernel 1: Phi = cos(D@W + b)/32 — K-concat 1536, 256x256 tile,
// 4-phase counted-vmcnt pipeline (validated r2-r9 — UNCHANGED).
// =====================================================================

#define READ_FA(FA, mh) do {                                                  \
    _Pragma("unroll")                                                         \
    for (int i_ = 0; i_ < 4; ++i_) {                                          \
        FA[i_][0] = *(const short8*)(A + (wm * 8 + (mh) * 4 + i_) * 1024      \
                                       + quad * 128 + ln * 8);                \
        FA[i_][1] = *(const short8*)(A + (wm * 8 + (mh) * 4 + i_) * 1024      \
                                       + 512 + quad * 128 + ln * 8);          \
    } } while (0)

#define READ_FB(FB, nh) do {                                                  \
    _Pragma("unroll")                                                         \
    for (int j_ = 0; j_ < 2; ++j_) {                                          \
        FB[j_][0] = *(const short8*)(B + (wn * 4 + (nh) * 2 + j_) * 1024      \
                                       + quad * 128 + ln * 8);                \
        FB[j_][1] = *(const short8*)(B + (wn * 4 + (nh) * 2 + j_) * 1024      \
                                       + 512 + quad * 128 + ln * 8);          \
    } } while (0)

#define MFMA16(MH, NH, FA, FB) do {                                           \
    __builtin_amdgcn_s_setprio(1);                                            \
    _Pragma("unroll")                                                         \
    for (int s_ = 0; s_ < 2; ++s_)                                            \
        _Pragma("unroll")                                                     \
        for (int i_ = 0; i_ < 4; ++i_)                                        \
            _Pragma("unroll")                                                 \
            for (int j_ = 0; j_ < 2; ++j_)                                    \
                acc[(MH) * 4 + i_][(NH) * 2 + j_] =                           \
                    __builtin_amdgcn_mfma_f32_16x16x32_bf16(                  \
                        FA[i_][s_], FB[j_][s_],                               \
                        acc[(MH) * 4 + i_][(NH) * 2 + j_], 0, 0, 0);          \
    __builtin_amdgcn_s_setprio(0);                                            \
} while (0)

__global__ __launch_bounds__(512, 2) void phi_mfma8p_kernel(
    const unsigned short* __restrict__ Dh, const unsigned short* __restrict__ Dl,
    const unsigned short* __restrict__ Wth, const unsigned short* __restrict__ Wtl,
    const float* __restrict__ bias, unsigned short* __restrict__ Phi)
{
    __shared__ unsigned short ldsA[2 * 16384];
    __shared__ unsigned short ldsB[2 * 16384];
    const int tid = threadIdx.x;
    const int w = tid >> 6, lane = tid & 63;
    const int wm = w >> 2, wn = w & 3;
    const int quad = lane >> 4, ln = lane & 15;

    const int bid = blockIdx.x;
    const int xcd = bid & 7, idx = bid >> 3;
    const int rb = (xcd >> 1) * 8 + (idx & 7);
    const int cb = (xcd & 1) * 4 + (idx >> 3);
    const int r0 = rb * 256;
    const int c0 = cb * 256;

    f32x4 acc[8][4];
    #pragma unroll
    for (int i = 0; i < 8; ++i)
        #pragma unroll
        for (int j = 0; j < 4; ++j)
            acc[i][j] = (f32x4)(0.0f);

    stage_ab(Dh, IN_F, r0, 0, ldsA, 0, 0, w, lane);
    stage_ab(Dh, IN_F, r0, 0, ldsA, 0, 1, w, lane);
    stage_ab(Dh, IN_F, r0, 0, ldsA, 1, 0, w, lane);
    stage_ab(Dh, IN_F, r0, 0, ldsA, 1, 1, w, lane);
    stageB_g(Wth, c0, 0, ldsB, 0, 0, w, lane);
    stageB_g(Wth, c0, 0, ldsB, 0, 1, w, lane);
    stageB_g(Wth, c0, 0, ldsB, 1, 0, w, lane);
    stageB_g(Wth, c0, 0, ldsB, 1, 1, w, lane);
    stage_ab(Dh, IN_F, r0, 64, ldsA + 16384, 0, 0, w, lane);
    stage_ab(Dh, IN_F, r0, 64, ldsA + 16384, 0, 1, w, lane);
    stageB_g(Wth, c0, 64, ldsB + 16384, 0, 0, w, lane);
    stageB_g(Wth, c0, 64, ldsB + 16384, 0, 1, w, lane);
    WAITVM(4);
    BARRIER();

    for (int t = 0; t < PHI_NT - 1; ++t) {
        const int buf = t & 1;
        const unsigned short* A = ldsA + buf * 16384;
        const unsigned short* B = ldsB + buf * 16384;
        unsigned short* curA = ldsA + buf * 16384;
        unsigned short* curB = ldsB + buf * 16384;
        unsigned short* othA = ldsA + (buf ^ 1) * 16384;
        unsigned short* othB = ldsB + (buf ^ 1) * 16384;
        const bool has2 = (t + 2) < PHI_NT;
        const int k1 = (t + 1) * 64, k2 = (t + 2) * 64;
        const int kk1 = k1 & 511, kk2 = k2 & 511;
        const unsigned short* A1 = (k1 >= 1024) ? Dl : Dh;
        const unsigned short* B1 = (k1 >= 1024) ? Wth : (k1 >= 512 ? Wtl : Wth);
        const unsigned short* A2 = (k2 >= 1024) ? Dl : Dh;
        const unsigned short* B2 = (k2 >= 1024) ? Wth : (k2 >= 512 ? Wtl : Wth);

        short8 fa[4][2], fb0[2][2], fb1[2][2];

        READ_FA(fa, 0);
        READ_FB(fb0, 0);
        stage_ab(A1, IN_F, r0, kk1, othA, 1, 0, w, lane);
        stage_ab(A1, IN_F, r0, kk1, othA, 1, 1, w, lane);
        BARRIER();
        MFMA16(0, 0, fa, fb0);
        BARRIER();

        READ_FB(fb1, 1);
        stageB_g(B1, c0, kk1, othB, 1, 0, w, lane);
        stageB_g(B1, c0, kk1, othB, 1, 1, w, lane);
        BARRIER();
        MFMA16(0, 1, fa, fb1);
        BARRIER();

        READ_FA(fa, 1);
        if (has2) { stage_ab(A2, IN_F, r0, kk2, curA, 0, 0, w, lane);
                    stage_ab(A2, IN_F, r0, kk2, curA, 0, 1, w, lane); }
        BARRIER();
        MFMA16(1, 0, fa, fb0);
        BARRIER();

        if (has2) { stageB_g(B2, c0, kk2, curB, 0, 0, w, lane);
                    stageB_g(B2, c0, kk2, curB, 0, 1, w, lane);
                    WAITVM(4); }
        else      { WAITVM(0); }
        BARRIER();
        MFMA16(1, 1, fa, fb1);
        BARRIER();
    }

    {
        asm volatile("" ::: "memory");
        const unsigned short* A = ldsA + ((PHI_NT - 1) & 1) * 16384;
        const unsigned short* B = ldsB + ((PHI_NT - 1) & 1) * 16384;
        short8 fa[4][2], fb0[2][2], fb1[2][2];
        READ_FA(fa, 0);
        READ_FB(fb0, 0);
        READ_FB(fb1, 1);
        MFMA16(0, 0, fa, fb0);
        MFMA16(0, 1, fa, fb1);
        READ_FA(fa, 1);
        MFMA16(1, 0, fa, fb0);
        MFMA16(1, 1, fa, fb1);
    }

    float bv[4];
    #pragma unroll
    for (int nt = 0; nt < 4; ++nt)
        bv[nt] = bias[c0 + wn * 64 + nt * 16 + ln];
    #pragma unroll
    for (int mt = 0; mt < 8; ++mt)
        #pragma unroll
        for (int nt = 0; nt < 4; ++nt) {
            int col = c0 + wn * 64 + nt * 16 + ln;
            #pragma unroll
            for (int reg = 0; reg < 4; ++reg) {
                int row = r0 + wm * 128 + mt * 16 + quad * 4 + reg;
                float z = acc[mt][nt][reg] + bv[nt];
                float p = __cosf(z) * INV_RFF_SCALAR;
                Phi[(size_t)row * RFF + col] = f32_to_bf16(p);
            }
        }
}

// =====================================================================
// Kernel 2: diag — r0-validated body EXACTLY (single-buffer 32 KiB LDS,
// high block-occupancy, no fence, no epilogue). r9's fused epilogue
// regressed 75 -> 277 µs via per-block __threadfence L2 writeback.
// =====================================================================
__global__ __launch_bounds__(256) void diag8_kernel(
    const unsigned char* __restrict__ Phi8, const unsigned char* __restrict__ CovU8,
    const unsigned short* __restrict__ Phi16, const float* __restrict__ Cd,
    float* __restrict__ diag)
{
    __shared__ __align__(16) unsigned char ldsA[16384];
    __shared__ __align__(16) unsigned char ldsB[16384];
    const int tid = threadIdx.x;
    const int w = tid >> 6, lane = tid & 63;
    const int wm = w >> 1, wn = w & 1;
    const int quad = lane >> 4, ln = lane & 15;
    const int J = 15 - blockIdx.x;
    const int r0 = blockIdx.y * 128;
    const int c0 = J * 128;
    const int kmax = (J + 1) * 128;

    f32x4 acc[4][4];
    #pragma unroll
    for (int i = 0; i < 4; ++i)
        #pragma unroll
        for (int j = 0; j < 4; ++j)
            acc[i][j] = (f32x4)(0.0f);

    for (int k0 = 0; k0 < kmax; k0 += 128) {
        __syncthreads();
        stage_tile8(Phi8,  r0, k0, ldsA, w, lane);
        stage_tile8(CovU8, c0, k0, ldsB, w, lane);
        __syncthreads();

        #pragma unroll
        for (int kb = 0; kb < 2; ++kb) {
            long2v fa[4], fb[4];
            #pragma unroll
            for (int t = 0; t < 4; ++t) {
                fa[t] = *(const long2v*)(ldsA + (((wm * 4 + t) * 128 + (kb * 4 + quad) * 16 + ln) << 4));
                fb[t] = *(const long2v*)(ldsB + (((wn * 4 + t) * 128 + (kb * 4 + quad) * 16 + ln) << 4));
            }
            #pragma unroll
            for (int mt = 0; mt < 4; ++mt)
                #pragma unroll
                for (int nt = 0; nt < 4; ++nt)
                    acc[mt][nt] = __builtin_amdgcn_mfma_f32_16x16x32_fp8_fp8(
                        fa[mt].x, fb[nt].x, acc[mt][nt], 0, 0, 0);
            #pragma unroll
            for (int mt = 0; mt < 4; ++mt)
                #pragma unroll
                for (int nt = 0; nt < 4; ++nt)
                    acc[mt][nt] = __builtin_amdgcn_mfma_f32_16x16x32_fp8_fp8(
                        fa[mt].y, fb[nt].y, acc[mt][nt], 0, 0, 0);
        }
    }

    float cd[4];
    #pragma unroll
    for (int nt = 0; nt < 4; ++nt)
        cd[nt] = 256.0f * Cd[c0 + wn * 64 + nt * 16 + ln];
    #pragma unroll
    for (int mt = 0; mt < 4; ++mt) {
        float psum[4] = {0.f, 0.f, 0.f, 0.f};
        #pragma unroll
        for (int nt = 0; nt < 4; ++nt) {
            int col = c0 + wn * 64 + nt * 16 + ln;
            #pragma unroll
            for (int reg = 0; reg < 4; ++reg) {
                int row = r0 + wm * 64 + mt * 16 + quad * 4 + reg;
                float pv = bf16_to_f32(Phi16[(size_t)row * RFF + col]);
                psum[reg] = fmaf(fmaf(cd[nt], pv, acc[mt][nt][reg]), pv, psum[reg]);
            }
        }
        #pragma unroll
        for (int off = 1; off < 16; off <<= 1)
            #pragma unroll
            for (int reg = 0; reg < 4; ++reg)
                psum[reg] += __shfl_xor(psum[reg], off, 16);
        if (ln == 0) {
            #pragma unroll
            for (int reg = 0; reg < 4; ++reg) {
                int row = r0 + wm * 64 + mt * 16 + quad * 4 + reg;
                atomicAdd(&diag[row], psum[reg] * (1.0f / 256.0f));
            }
        }
    }
}

// =====================================================================
// Kernel 3: pred — r4-validated min-2-phase counted pipeline (77 µs),
// inline bias + diag-scale epilogue (diag ready: launched after diag8).
// 256M x 128N tile, BK=64, 512 thr (8 waves 4Mx2N).
// =====================================================================
__global__ __launch_bounds__(512, 2) void pred_min2_kernel(
    const unsigned short* __restrict__ Phi, const unsigned short* __restrict__ Lw,
    const float* __restrict__ Lb, const float* __restrict__ diag,
    float* __restrict__ out)
{
    __shared__ unsigned short ldsA[2 * 16384];   // 64 KiB
    __shared__ unsigned short ldsB[2 * 8192];    // 32 KiB
    const int tid = threadIdx.x;
    const int w = tid >> 6, lane = tid & 63;
    const int wm = w >> 1, wn = w & 1;
    const int quad = lane >> 4, ln = lane & 15;

    // XCD-aware: each XCD owns 4 contiguous row-strips x all 8 col-blocks
    const int bid = blockIdx.x;
    const int xcd = bid & 7, idx = bid >> 3;
    const int rb = xcd * 4 + (idx >> 3);
    const int cb = idx & 7;
    const int r0 = rb * 256;
    const int c0 = cb * 128;

    f32x4 acc[4][4];
    #pragma unroll
    for (int i = 0; i < 4; ++i)
        #pragma unroll
        for (int j = 0; j < 4; ++j)
            acc[i][j] = (f32x4)(0.0f);

    // prologue: tile 0 -> buf0 (6 calls)
    stage_ab(Phi, RFF, r0, 0, ldsA, 0, 0, w, lane);
    stage_ab(Phi, RFF, r0, 0, ldsA, 1, 0, w, lane);
    stage_ab(Phi, RFF, r0, 0, ldsA, 0, 1, w, lane);
    stage_ab(Phi, RFF, r0, 0, ldsA, 1, 1, w, lane);
    stage_ab(Lw,  RFF, c0, 0, ldsB, 0, 0, w, lane);
    stage_ab(Lw,  RFF, c0, 0, ldsB, 1, 0, w, lane);
    WAITVM(0);
    BARRIER();

    for (int t = 0; t < PRED_NT; ++t) {
        const int buf = t & 1;
        const unsigned short* A = ldsA + buf * 16384;
        const unsigned short* B = ldsB + buf * 8192;

        // issue-early: stage tile t+1 into the other buffer
        if (t + 1 < PRED_NT) {
            const int kk = (t + 1) * 64;
            unsigned short* nA = ldsA + (buf ^ 1) * 16384;
            unsigned short* nB = ldsB + (buf ^ 1) * 8192;
            stage_ab(Phi, RFF, r0, kk, nA, 0, 0, w, lane);
            stage_ab(Phi, RFF, r0, kk, nA, 1, 0, w, lane);
            stage_ab(Phi, RFF, r0, kk, nA, 0, 1, w, lane);
            stage_ab(Phi, RFF, r0, kk, nA, 1, 1, w, lane);
            stage_ab(Lw,  RFF, c0, kk, nB, 0, 0, w, lane);
            stage_ab(Lw,  RFF, c0, kk, nB, 1, 0, w, lane);
        }

        // fat compute phase: 16 ds_read_b128 + 32 MFMA
        short8 fa[4][2], fb[4][2];
        #pragma unroll
        for (int i_ = 0; i_ < 4; ++i_) {
            fa[i_][0] = *(const short8*)(A + (wm * 4 + i_) * 1024 + quad * 128 + ln * 8);
            fa[i_][1] = *(const short8*)(A + (wm * 4 + i_) * 1024 + 512 + quad * 128 + ln * 8);
        }
        #pragma unroll
        for (int j_ = 0; j_ < 4; ++j_) {
            fb[j_][0] = *(const short8*)(B + (wn * 4 + j_) * 1024 + quad * 128 + ln * 8);
            fb[j_][1] = *(const short8*)(B + (wn * 4 + j_) * 1024 + 512 + quad * 128 + ln * 8);
        }
        __builtin_amdgcn_s_setprio(1);
        #pragma unroll
        for (int s_ = 0; s_ < 2; ++s_)
            #pragma unroll
            for (int i_ = 0; i_ < 4; ++i_)
                #pragma unroll
                for (int j_ = 0; j_ < 4; ++j_)
                    acc[i_][j_] = __builtin_amdgcn_mfma_f32_16x16x32_bf16(
                        fa[i_][s_], fb[j_][s_], acc[i_][j_], 0, 0, 0);
        __builtin_amdgcn_s_setprio(0);

        WAITVM(0);
        BARRIER();
    }

    // ---- epilogue: (acc + Lb) / sqrt(1 + 25*diag) ----
    #pragma unroll
    for (int mt = 0; mt < 4; ++mt) {
        float s[4];
        #pragma unroll
        for (int reg = 0; reg < 4; ++reg) {
            int row = r0 + wm * 64 + mt * 16 + quad * 4 + reg;
            s[reg] = 1.0f / sqrtf(1.0f + MEAN_FIELD * diag[row]);
        }
        #pragma unroll
        for (int nt = 0; nt < 4; ++nt) {
            int col = c0 + wn * 64 + nt * 16 + ln;
            if (col < OUT_F) {
                float bv = Lb[col];
                #pragma unroll
                for (int reg = 0; reg < 4; ++reg) {
                    int row = r0 + wm * 64 + mt * 16 + quad * 4 + reg;
                    out[(size_t)row * OUT_F + col] = (acc[mt][nt][reg] + bv) * s[reg];
                }
            }
        }
    }
}

extern "C" void kernel_launch(void* const* d_in, const int* in_sizes, int n_in,
                              void* d_out, int out_size, void* d_ws, size_t ws_size,
                              hipStream_t stream) {
    const float* D    = (const float*)d_in[0];
    const float* W    = (const float*)d_in[1];
    const float* bias = (const float*)d_in[2];
    const float* Lw   = (const float*)d_in[3];
    const float* Lb   = (const float*)d_in[4];
    const float* cov  = (const float*)d_in[5];
    float* out = (float*)d_out;

    char* p = (char*)d_ws;
    unsigned short* Phi16 = (unsigned short*)p;  p += (size_t)N_ROWS * RFF * 2;   // 32 MiB
    unsigned char*  Phi8  = (unsigned char*)p;   // alias of Dh+Dl region (16 MiB)
    unsigned short* Dh    = (unsigned short*)p;  p += (size_t)N_ROWS * IN_F * 2;  // 8 MiB
    unsigned short* Dl    = (unsigned short*)p;  p += (size_t)N_ROWS * IN_F * 2;  // 8 MiB
    unsigned short* Wth   = (unsigned short*)p;  p += (size_t)RFF * IN_F * 2;     // 2 MiB
    unsigned short* Wtl   = (unsigned short*)p;  p += (size_t)RFF * IN_F * 2;     // 2 MiB
    unsigned short* Lw16  = (unsigned short*)p;  p += (size_t)OUT_PAD * RFF * 2;  // 4 MiB
    unsigned char*  CovU8 = (unsigned char*)p;                                    // 4 MiB used
    float*          Cd    = (float*)(p + (size_t)RFF * RFF);                      // 8 KiB (in pad)
    p += (size_t)RFF * RFF * 2;                                                   // 8 MiB region
    float* diag           = (float*)p;                                            // 32 KiB

    mega_conv_kernel<<<dim3(10504), dim3(256), 0, stream>>>(
        D, W, Lw, cov, Dh, Dl, Wth, Wtl, Lw16, CovU8, Cd, diag);

    phi_mfma8p_kernel<<<dim3(256), dim3(512), 0, stream>>>(Dh, Dl, Wth, Wtl, bias, Phi16);

    conv_phi8_kernel<<<dim3(N_ROWS * RFF / 4 / 256), dim3(256), 0, stream>>>(Phi16, Phi8);

    diag8_kernel<<<dim3(16, N_ROWS / 128), dim3(256), 0, stream>>>(Phi8, CovU8, Phi16, Cd, diag);

    pred_min2_kernel<<<dim3(256), dim3(512), 0, stream>>>(Phi16, Lw16, Lb, diag, out);
}